// Round 1
// baseline (271.127 us; speedup 1.0000x reference)
//
#include <hip/hip_runtime.h>
#include <stdint.h>

#define DI __device__ __forceinline__

typedef float f32x4 __attribute__((ext_vector_type(4)));
typedef short bf16x8 __attribute__((ext_vector_type(8)));

DI uint16_t f2bf(float f) {
    union { float f; uint32_t u; } v; v.f = f;
    uint32_t r = v.u + 0x7FFF + ((v.u >> 16) & 1);
    return (uint16_t)(r >> 16);
}
DI float bf2f(uint16_t h) {
    union { uint32_t u; float f; } v; v.u = ((uint32_t)h) << 16;
    return v.f;
}
// async global->LDS, 16B per lane; LDS dest = wave-uniform base + lane*16
DI void gl_lds16(const void* g, void* l) {
    __builtin_amdgcn_global_load_lds(
        (__attribute__((address_space(1))) void*)(uintptr_t)g,
        (__attribute__((address_space(3))) void*)(uintptr_t)l,
        16, 0, 0);
}

// ---------------- kernel 0: zero accumulators + Wc^T bf16 (pad 31->32) ----
__global__ void k_init(const float* __restrict__ Wc, uint16_t* __restrict__ WcT,
                       float* __restrict__ zeros) {
    int tid = threadIdx.x;
    for (int i = tid; i < 516; i += 256) zeros[i] = 0.f;          // colsum[512] + accs[4]
    for (int idx = tid; idx < 32 * 256; idx += 256) {
        int n = idx >> 8, k = idx & 255;
        WcT[idx] = (n < 31) ? f2bf(Wc[k * 31 + n]) : (uint16_t)0;
    }
}

// ---------------- kernel 1: Wb [2048][256] -> WbT bf16 [256][2048] --------
__global__ void k_transpose_wb(const float* __restrict__ Wb, uint16_t* __restrict__ WbT) {
    __shared__ float t[32][33];
    int kb = blockIdx.x, nb = blockIdx.y;
    int tx = threadIdx.x & 31, ty0 = (threadIdx.x >> 5) * 4;
    for (int i = 0; i < 4; ++i)
        t[ty0 + i][tx] = Wb[(kb * 32 + ty0 + i) * 256 + nb * 32 + tx];
    __syncthreads();
    for (int i = 0; i < 4; ++i)
        WbT[(nb * 32 + ty0 + i) * 2048 + kb * 32 + tx] = f2bf(t[tx][ty0 + i]);
}

// ---------------- kernel 2: Y = relu([src;tar] @ Wb + bb), bf16 out -------
// tile 32(m) x 256(n), BK=64, 256 blocks. LDS layout per 32-k chunk:
// off = kb*(TM*64) + r*64 + pos*16, chunk stored at pos = c ^ (r&3) ^ ((r>>2)&3)
__launch_bounds__(256)
__global__ void k_bottleneck(const float* __restrict__ src, const float* __restrict__ tgt,
                             const uint16_t* __restrict__ WbT, const float* __restrict__ bb,
                             uint16_t* __restrict__ Y) {
    __shared__ __align__(16) uint8_t lds[36864];   // A: 4KB @0, B: 32KB @4096
    int tid = threadIdx.x;
    int lane = tid & 63, w = tid >> 6;
    int m0 = blockIdx.x * 32;
    const float* X = (m0 < 4096) ? (src + (size_t)m0 * 2048)
                                 : (tgt + (size_t)(m0 - 4096) * 2048);
    // A-staging assignment: 8 fp32 per thread
    int ar = tid >> 3, akb = (tid >> 2) & 1, ap = tid & 3;
    int ac = ap ^ (ar & 3) ^ ((ar >> 2) & 3);
    const float* Ag = X + ar * 2048 + akb * 32 + ac * 8;
    uint8_t* Aw = lds + akb * 2048 + ar * 64 + ap * 16;
    int cc = (lane >> 4) ^ (lane & 3) ^ ((lane >> 2) & 3);
    f32x4 acc[2][4] = {};
    for (int t = 0; t < 32; ++t) {
        int k0 = t * 64;
        if (t) __syncthreads();
        // B stage: 8 segs/wave via global_load_lds
        for (int i = 0; i < 8; ++i) {
            int s = w * 8 + i;
            int kb = s >> 4, r0 = (s & 15) * 16;
            int r = r0 + (lane >> 2), p = lane & 3;
            int c = p ^ (r & 3) ^ ((r >> 2) & 3);
            gl_lds16(WbT + r * 2048 + k0 + kb * 32 + c * 8, lds + 4096 + s * 1024);
        }
        // A stage: fp32 -> bf16 convert
        float4 x0 = *(const float4*)(Ag + k0);
        float4 x1 = *(const float4*)(Ag + k0 + 4);
        uint4 u;
        u.x = (uint32_t)f2bf(x0.x) | ((uint32_t)f2bf(x0.y) << 16);
        u.y = (uint32_t)f2bf(x0.z) | ((uint32_t)f2bf(x0.w) << 16);
        u.z = (uint32_t)f2bf(x1.x) | ((uint32_t)f2bf(x1.y) << 16);
        u.w = (uint32_t)f2bf(x1.z) | ((uint32_t)f2bf(x1.w) << 16);
        *(uint4*)Aw = u;
        __syncthreads();
        for (int kb = 0; kb < 2; ++kb) {
            bf16x8 a[2], b[4];
            for (int mi = 0; mi < 2; ++mi) {
                int r = mi * 16 + (lane & 15);
                a[mi] = *(const bf16x8*)(lds + kb * 2048 + r * 64 + cc * 16);
            }
            for (int nf = 0; nf < 4; ++nf) {
                int rn = w * 64 + nf * 16 + (lane & 15);
                b[nf] = *(const bf16x8*)(lds + 4096 + kb * 16384 + rn * 64 + cc * 16);
            }
            for (int mi = 0; mi < 2; ++mi)
                for (int nf = 0; nf < 4; ++nf)
                    acc[mi][nf] = __builtin_amdgcn_mfma_f32_16x16x32_bf16(
                        a[mi], b[nf], acc[mi][nf], 0, 0, 0);
        }
    }
    for (int mi = 0; mi < 2; ++mi)
        for (int nf = 0; nf < 4; ++nf) {
            int col = w * 64 + nf * 16 + (lane & 15);
            float bias = bb[col];
            for (int j = 0; j < 4; ++j) {
                int row = m0 + mi * 16 + (lane >> 4) * 4 + j;
                float v = acc[mi][nf][j] + bias;
                v = fmaxf(v, 0.f);
                Y[(size_t)row * 256 + col] = f2bf(v);
            }
        }
}

// ---------------- kernel 3: row sum-of-squares --------------------------
__global__ void k_rowstats(const uint16_t* __restrict__ Y, float* __restrict__ s2t2) {
    int row = blockIdx.x * 4 + (threadIdx.x >> 6);
    int lane = threadIdx.x & 63;
    ushort4 v = *(const ushort4*)(Y + (size_t)row * 256 + lane * 4);
    float a = bf2f(v.x), b = bf2f(v.y), c = bf2f(v.z), d = bf2f(v.w);
    float s = a * a + b * b + c * c + d * d;
    for (int m = 1; m < 64; m <<= 1) s += __shfl_xor(s, m);
    if (lane == 0) s2t2[row] = s;
}

// ---------------- kernel 4: column sums (for MMD) -----------------------
__global__ void k_colsum(const uint16_t* __restrict__ Y, float* __restrict__ colsum) {
    int c = threadIdx.x;
    int r0 = blockIdx.x * 128;
    float acc = 0.f;
    for (int r = r0; r < r0 + 128; ++r) acc += bf2f(Y[(size_t)r * 256 + c]);
    atomicAdd(&colsum[(r0 < 4096 ? 0 : 256) + c], acc);
}

// ---------------- kernel 5: classifier + softmax margins + CE -----------
__launch_bounds__(256)
__global__ void k_classifier(const uint16_t* __restrict__ Y, const uint16_t* __restrict__ WcT,
                             const float* __restrict__ bc, const int* __restrict__ labels,
                             float* __restrict__ out_margin, float* __restrict__ ce_acc) {
    __shared__ __align__(16) uint8_t lds[49152];  // A 32KB @0, B 16KB @32768
    int tid = threadIdx.x, lane = tid & 63, w = tid >> 6;
    int m0 = blockIdx.x * 64;
    int cc = (lane >> 4) ^ (lane & 3) ^ ((lane >> 2) & 3);
    for (int s = w; s < 48; s += 4) {
        int r, p, c;
        if (s < 32) {
            int kb = s >> 2, r0 = (s & 3) * 16;
            r = r0 + (lane >> 2); p = lane & 3;
            c = p ^ (r & 3) ^ ((r >> 2) & 3);
            gl_lds16(Y + (size_t)(m0 + r) * 256 + kb * 32 + c * 8, lds + s * 1024);
        } else {
            int s2 = s - 32;
            int kb = s2 >> 1, r0 = (s2 & 1) * 16;
            r = r0 + (lane >> 2); p = lane & 3;
            c = p ^ (r & 3) ^ ((r >> 2) & 3);
            gl_lds16(WcT + r * 256 + kb * 32 + c * 8, lds + 32768 + s2 * 1024);
        }
    }
    __syncthreads();
    f32x4 acc[2] = {};
    for (int kb = 0; kb < 8; ++kb) {
        int r = w * 16 + (lane & 15);
        bf16x8 a = *(const bf16x8*)(lds + kb * 4096 + r * 64 + cc * 16);
        for (int nf = 0; nf < 2; ++nf) {
            int rn = nf * 16 + (lane & 15);
            bf16x8 b = *(const bf16x8*)(lds + 32768 + kb * 2048 + rn * 64 + cc * 16);
            acc[nf] = __builtin_amdgcn_mfma_f32_16x16x32_bf16(a, b, acc[nf], 0, 0, 0);
        }
    }
    int c0 = lane & 15, c1 = 16 + c0;
    float bc0 = bc[c0];
    float bc1 = (c1 < 31) ? bc[c1] : 0.f;
    bool is_src = (m0 < 4096);
    float ce_local = 0.f;
    for (int j = 0; j < 4; ++j) {
        int row = m0 + w * 16 + (lane >> 4) * 4 + j;
        float v0 = acc[0][j] + bc0;
        float v1 = (c1 < 31) ? (acc[1][j] + bc1) : -1e30f;
        float mx = fmaxf(v0, v1);
        for (int m = 1; m < 16; m <<= 1) mx = fmaxf(mx, __shfl_xor(mx, m, 16));
        float e0 = __expf(v0 - mx);
        float e1 = (c1 < 31) ? __expf(v1 - mx) : 0.f;
        float ssum = e0 + e1;
        for (int m = 1; m < 16; m <<= 1) ssum += __shfl_xor(ssum, m, 16);
        float inv = 1.f / ssum;
        float conf0 = e0 * inv, conf1 = e1 * inv;
        int lab;
        if (is_src) {
            lab = labels[row];
        } else {
            float bv; int bi;
            if (v0 >= v1) { bv = v0; bi = c0; } else { bv = v1; bi = c1; }
            for (int m = 1; m < 16; m <<= 1) {
                float ov = __shfl_xor(bv, m, 16);
                int oi = __shfl_xor(bi, m, 16);
                if (ov > bv || (ov == bv && oi < bi)) { bv = ov; bi = oi; }
            }
            lab = bi;
        }
        float tc = (c0 == lab ? conf0 : 0.f) + (c1 == lab ? conf1 : 0.f);
        for (int m = 1; m < 16; m <<= 1) tc += __shfl_xor(tc, m, 16);
        float ex = fmaxf(c0 == lab ? -1.f : conf0,
                         (c1 == lab || c1 >= 31) ? -1.f : conf1);
        for (int m = 1; m < 16; m <<= 1) ex = fmaxf(ex, __shfl_xor(ex, m, 16));
        if (c0 == 0) out_margin[row] = tc - ex;
        if (is_src) {
            float vl = (c0 == lab) ? v0 : ((c1 == lab) ? v1 : -1e30f);
            for (int m = 1; m < 16; m <<= 1) vl = fmaxf(vl, __shfl_xor(vl, m, 16));
            if (c0 == 0) ce_local += -(vl - mx - __logf(ssum));
        }
    }
    if (is_src) {
        ce_local += __shfl_xor(ce_local, 16);
        ce_local += __shfl_xor(ce_local, 32);
        if (lane == 0) atomicAdd(ce_acc, ce_local);
    }
}

// ---------------- kernel 6: pairwise d2 -> exp sums ---------------------
// 128x128 tile, K=256 staged in 2 halves of 64KB LDS
__launch_bounds__(256)
__global__ void k_pairwise(const uint16_t* __restrict__ Y, const float* __restrict__ s2t2,
                           float* __restrict__ gk) {
    __shared__ __align__(16) uint8_t lds[65536];  // A 32KB @0, B 32KB @32768
    int tid = threadIdx.x, lane = tid & 63, w = tid >> 6;
    int m0 = blockIdx.x * 128, n0 = blockIdx.y * 128;
    int cc = (lane >> 4) ^ (lane & 3) ^ ((lane >> 2) & 3);
    int wm = (w & 1) * 64, wn = (w >> 1) * 64;
    f32x4 acc[4][4] = {};
    for (int h = 0; h < 2; ++h) {
        if (h) __syncthreads();
        int k0 = h * 128;
        for (int i = 0; i < 8; ++i) {
            int s = w * 8 + i;
            int kb = s >> 3, r0 = (s & 7) * 16;
            int r = r0 + (lane >> 2), p = lane & 3;
            int c = p ^ (r & 3) ^ ((r >> 2) & 3);
            gl_lds16(Y + (size_t)(m0 + r) * 256 + k0 + kb * 32 + c * 8, lds + s * 1024);
            gl_lds16(Y + (size_t)(4096 + n0 + r) * 256 + k0 + kb * 32 + c * 8,
                     lds + 32768 + s * 1024);
        }
        __syncthreads();
        for (int kb = 0; kb < 4; ++kb) {
            bf16x8 a[4], b[4];
            for (int mi = 0; mi < 4; ++mi) {
                int r = wm + mi * 16 + (lane & 15);
                a[mi] = *(const bf16x8*)(lds + kb * 8192 + r * 64 + cc * 16);
            }
            for (int nf = 0; nf < 4; ++nf) {
                int rn = wn + nf * 16 + (lane & 15);
                b[nf] = *(const bf16x8*)(lds + 32768 + kb * 8192 + rn * 64 + cc * 16);
            }
            for (int mi = 0; mi < 4; ++mi)
                for (int nf = 0; nf < 4; ++nf)
                    acc[mi][nf] = __builtin_amdgcn_mfma_f32_16x16x32_bf16(
                        a[mi], b[nf], acc[mi][nf], 0, 0, 0);
        }
    }
    float t2v[4];
    for (int nf = 0; nf < 4; ++nf)
        t2v[nf] = s2t2[4096 + n0 + wn + nf * 16 + (lane & 15)];
    float g1 = 0.f, g5 = 0.f;
    for (int mi = 0; mi < 4; ++mi) {
        int rbase = m0 + wm + mi * 16 + (lane >> 4) * 4;
        float s2v[4];
        for (int j = 0; j < 4; ++j) s2v[j] = s2t2[rbase + j];
        for (int nf = 0; nf < 4; ++nf)
            for (int j = 0; j < 4; ++j) {
                float d2 = s2v[j] + t2v[nf] - 2.f * acc[mi][nf][j];
                d2 = fmaxf(d2, 0.f);
                g1 += __expf(-0.5f * d2);
                g5 += __expf(-0.02f * d2);
            }
    }
    for (int m = 1; m < 64; m <<= 1) { g1 += __shfl_xor(g1, m); g5 += __shfl_xor(g5, m); }
    if (lane == 0) { atomicAdd(&gk[0], g1); atomicAdd(&gk[1], g5); }
}

// ---------------- kernel 7: finalize scalars ----------------------------
__global__ void k_finalize(const float* __restrict__ colsum, const float* __restrict__ accs,
                           float* __restrict__ d_out) {
    __shared__ float red[4];
    int tid = threadIdx.x, lane = tid & 63, w = tid >> 6;
    float delta = (colsum[tid] - colsum[256 + tid]) * (1.f / 4096.f);
    float sq = delta * delta;
    for (int m = 1; m < 64; m <<= 1) sq += __shfl_xor(sq, m);
    if (lane == 0) red[w] = sq;
    __syncthreads();
    if (tid == 0) {
        d_out[0] = accs[0] * (1.f / 4096.f);
        d_out[1] = red[0] + red[1] + red[2] + red[3];
        d_out[2] = accs[1] * 5.9604644775390625e-08f;
        d_out[3] = accs[2] * 5.9604644775390625e-08f;
    }
}

extern "C" void kernel_launch(void* const* d_in, const int* in_sizes, int n_in,
                              void* d_out, int out_size, void* d_ws, size_t ws_size,
                              hipStream_t stream) {
    const float* source = (const float*)d_in[0];
    const float* target = (const float*)d_in[1];
    const float* Wb     = (const float*)d_in[2];
    const float* bb     = (const float*)d_in[3];
    const float* Wc     = (const float*)d_in[4];
    const float* bc     = (const float*)d_in[5];
    const int*   labels = (const int*)d_in[6];
    float* out = (float*)d_out;
    uint8_t* ws = (uint8_t*)d_ws;

    uint16_t* Y    = (uint16_t*)(ws);                 // 8192*256*2 = 4 MB
    uint16_t* WbT  = (uint16_t*)(ws + 4194304);       // 1 MB
    uint16_t* WcT  = (uint16_t*)(ws + 5242880);       // 16 KB
    float*    s2t2 = (float*)(ws + 5259264);          // 32 KB
    float*    colsum = (float*)(ws + 5292032);        // 512 floats
    float*    accs = colsum + 512;                    // [ce, gk1, gk5, pad]

    k_init<<<1, 256, 0, stream>>>(Wc, WcT, colsum);
    k_transpose_wb<<<dim3(64, 8), 256, 0, stream>>>(Wb, WbT);
    k_bottleneck<<<256, 256, 0, stream>>>(source, target, WbT, bb, Y);
    k_rowstats<<<2048, 256, 0, stream>>>(Y, s2t2);
    k_colsum<<<64, 256, 0, stream>>>(Y, colsum);
    k_classifier<<<128, 256, 0, stream>>>(Y, WcT, bc, labels, out + 4, accs);
    k_pairwise<<<dim3(32, 32), 256, 0, stream>>>(Y, s2t2, accs + 1);
    k_finalize<<<1, 256, 0, stream>>>(colsum, accs, out);
}

// Round 2
// 179.017 us; speedup vs baseline: 1.5145x; 1.5145x over previous
//
#include <hip/hip_runtime.h>
#include <stdint.h>

#define DI __device__ __forceinline__

typedef float f32x4 __attribute__((ext_vector_type(4)));
typedef short bf16x8 __attribute__((ext_vector_type(8)));

DI uint16_t f2bf(float f) {
    union { float f; uint32_t u; } v; v.f = f;
    uint32_t r = v.u + 0x7FFF + ((v.u >> 16) & 1);
    return (uint16_t)(r >> 16);
}
DI float bf2f(uint16_t h) {
    union { uint32_t u; float f; } v; v.u = ((uint32_t)h) << 16;
    return v.f;
}
// async global->LDS, 16B per lane; LDS dest = wave-uniform base + lane*16
DI void gl_lds16(const void* g, void* l) {
    __builtin_amdgcn_global_load_lds(
        (__attribute__((address_space(1))) void*)(uintptr_t)g,
        (__attribute__((address_space(3))) void*)(uintptr_t)l,
        16, 0, 0);
}

// ---------------- kernel 0: zero ce acc + Wc^T bf16 (pad 31->32) ----------
__global__ void k_init(const float* __restrict__ Wc, uint16_t* __restrict__ WcT,
                       float* __restrict__ accs) {
    int tid = threadIdx.x;
    if (tid < 4) accs[tid] = 0.f;
    for (int idx = tid; idx < 32 * 256; idx += 256) {
        int n = idx >> 8, k = idx & 255;
        WcT[idx] = (n < 31) ? f2bf(Wc[k * 31 + n]) : (uint16_t)0;
    }
}

// ---------------- kernel 1: Wb [2048][256] -> WbT bf16 [256][2048] --------
__global__ void k_transpose_wb(const float* __restrict__ Wb, uint16_t* __restrict__ WbT) {
    __shared__ float t[32][33];
    int kb = blockIdx.x, nb = blockIdx.y;
    int tx = threadIdx.x & 31, ty0 = (threadIdx.x >> 5) * 4;
    for (int i = 0; i < 4; ++i)
        t[ty0 + i][tx] = Wb[(kb * 32 + ty0 + i) * 256 + nb * 32 + tx];
    __syncthreads();
    for (int i = 0; i < 4; ++i)
        WbT[(nb * 32 + ty0 + i) * 2048 + kb * 32 + tx] = f2bf(t[tx][ty0 + i]);
}

// ---------------- kernel 2: Y = relu([src;tar] @ Wb + bb), bf16 out -------
// tile 32(m) x 128(n), BK=64, grid 512 -> 2 blocks/CU (overlap drain/compute)
__launch_bounds__(256)
__global__ void k_bottleneck(const float* __restrict__ src, const float* __restrict__ tgt,
                             const uint16_t* __restrict__ WbT, const float* __restrict__ bb,
                             uint16_t* __restrict__ Y) {
    __shared__ __align__(16) uint8_t lds[20480];   // A: 4KB @0, B: 16KB @4096
    int tid = threadIdx.x;
    int lane = tid & 63, w = tid >> 6;
    int bm = blockIdx.x >> 1, bn = blockIdx.x & 1;   // N-halves of same A adjacent
    int m0 = bm * 32;
    const float* X = (m0 < 4096) ? (src + (size_t)m0 * 2048)
                                 : (tgt + (size_t)(m0 - 4096) * 2048);
    // A-staging assignment: 8 fp32 per thread
    int ar = tid >> 3, akb = (tid >> 2) & 1, ap = tid & 3;
    int ac = ap ^ (ar & 3) ^ ((ar >> 2) & 3);
    const float* Ag = X + ar * 2048 + akb * 32 + ac * 8;
    uint8_t* Aw = lds + akb * 2048 + ar * 64 + ap * 16;
    int cc = (lane >> 4) ^ (lane & 3) ^ ((lane >> 2) & 3);
    f32x4 acc[2][2] = {};
    for (int t = 0; t < 32; ++t) {
        int k0 = t * 64;
        if (t) __syncthreads();
        // B stage: 4 segs/wave via global_load_lds (16 segs of 1KB total)
        for (int i = 0; i < 4; ++i) {
            int s = w * 4 + i;
            int kb = s >> 3, r0 = (s & 7) * 16;
            int r = r0 + (lane >> 2), p = lane & 3;
            int c = p ^ (r & 3) ^ ((r >> 2) & 3);
            gl_lds16(WbT + (size_t)(bn * 128 + r) * 2048 + k0 + kb * 32 + c * 8,
                     lds + 4096 + s * 1024);
        }
        // A stage: fp32 -> bf16 convert
        float4 x0 = *(const float4*)(Ag + k0);
        float4 x1 = *(const float4*)(Ag + k0 + 4);
        uint4 u;
        u.x = (uint32_t)f2bf(x0.x) | ((uint32_t)f2bf(x0.y) << 16);
        u.y = (uint32_t)f2bf(x0.z) | ((uint32_t)f2bf(x0.w) << 16);
        u.z = (uint32_t)f2bf(x1.x) | ((uint32_t)f2bf(x1.y) << 16);
        u.w = (uint32_t)f2bf(x1.z) | ((uint32_t)f2bf(x1.w) << 16);
        *(uint4*)Aw = u;
        __syncthreads();
        for (int kb = 0; kb < 2; ++kb) {
            bf16x8 a[2], b[2];
            for (int mi = 0; mi < 2; ++mi) {
                int r = mi * 16 + (lane & 15);
                a[mi] = *(const bf16x8*)(lds + kb * 2048 + r * 64 + cc * 16);
            }
            for (int nf = 0; nf < 2; ++nf) {
                int rn = w * 32 + nf * 16 + (lane & 15);
                b[nf] = *(const bf16x8*)(lds + 4096 + kb * 8192 + rn * 64 + cc * 16);
            }
            for (int mi = 0; mi < 2; ++mi)
                for (int nf = 0; nf < 2; ++nf)
                    acc[mi][nf] = __builtin_amdgcn_mfma_f32_16x16x32_bf16(
                        a[mi], b[nf], acc[mi][nf], 0, 0, 0);
        }
    }
    for (int mi = 0; mi < 2; ++mi)
        for (int nf = 0; nf < 2; ++nf) {
            int col = bn * 128 + w * 32 + nf * 16 + (lane & 15);
            float bias = bb[col];
            for (int j = 0; j < 4; ++j) {
                int row = m0 + mi * 16 + (lane >> 4) * 4 + j;
                float v = acc[mi][nf][j] + bias;
                v = fmaxf(v, 0.f);
                Y[(size_t)row * 256 + col] = f2bf(v);
            }
        }
}

// ---------------- kernel 3: row sum-of-squares --------------------------
__global__ void k_rowstats(const uint16_t* __restrict__ Y, float* __restrict__ s2t2) {
    int row = blockIdx.x * 4 + (threadIdx.x >> 6);
    int lane = threadIdx.x & 63;
    ushort4 v = *(const ushort4*)(Y + (size_t)row * 256 + lane * 4);
    float a = bf2f(v.x), b = bf2f(v.y), c = bf2f(v.z), d = bf2f(v.w);
    float s = a * a + b * b + c * c + d * d;
    for (int m = 1; m < 64; m <<= 1) s += __shfl_xor(s, m);
    if (lane == 0) s2t2[row] = s;
}

// ---------------- kernel 4: column partial sums (no atomics) ------------
__global__ void k_colsum(const uint16_t* __restrict__ Y, float* __restrict__ part) {
    int c = threadIdx.x;
    int r0 = blockIdx.x * 64;
    float acc = 0.f;
    for (int r = r0; r < r0 + 64; ++r) acc += bf2f(Y[(size_t)r * 256 + c]);
    part[blockIdx.x * 256 + c] = acc;
}

// ---------------- kernel 5: classifier + softmax margins + CE -----------
__launch_bounds__(256)
__global__ void k_classifier(const uint16_t* __restrict__ Y, const uint16_t* __restrict__ WcT,
                             const float* __restrict__ bc, const int* __restrict__ labels,
                             float* __restrict__ out_margin, float* __restrict__ ce_acc) {
    __shared__ __align__(16) uint8_t lds[49152];  // A 32KB @0, B 16KB @32768
    int tid = threadIdx.x, lane = tid & 63, w = tid >> 6;
    int m0 = blockIdx.x * 64;
    int cc = (lane >> 4) ^ (lane & 3) ^ ((lane >> 2) & 3);
    for (int s = w; s < 48; s += 4) {
        int r, p, c;
        if (s < 32) {
            int kb = s >> 2, r0 = (s & 3) * 16;
            r = r0 + (lane >> 2); p = lane & 3;
            c = p ^ (r & 3) ^ ((r >> 2) & 3);
            gl_lds16(Y + (size_t)(m0 + r) * 256 + kb * 32 + c * 8, lds + s * 1024);
        } else {
            int s2 = s - 32;
            int kb = s2 >> 1, r0 = (s2 & 1) * 16;
            r = r0 + (lane >> 2); p = lane & 3;
            c = p ^ (r & 3) ^ ((r >> 2) & 3);
            gl_lds16(WcT + r * 256 + kb * 32 + c * 8, lds + 32768 + s2 * 1024);
        }
    }
    __syncthreads();
    f32x4 acc[2] = {};
    for (int kb = 0; kb < 8; ++kb) {
        int r = w * 16 + (lane & 15);
        bf16x8 a = *(const bf16x8*)(lds + kb * 4096 + r * 64 + cc * 16);
        for (int nf = 0; nf < 2; ++nf) {
            int rn = nf * 16 + (lane & 15);
            bf16x8 b = *(const bf16x8*)(lds + 32768 + kb * 2048 + rn * 64 + cc * 16);
            acc[nf] = __builtin_amdgcn_mfma_f32_16x16x32_bf16(a, b, acc[nf], 0, 0, 0);
        }
    }
    int c0 = lane & 15, c1 = 16 + c0;
    float bc0 = bc[c0];
    float bc1 = (c1 < 31) ? bc[c1] : 0.f;
    bool is_src = (m0 < 4096);
    float ce_local = 0.f;
    for (int j = 0; j < 4; ++j) {
        int row = m0 + w * 16 + (lane >> 4) * 4 + j;
        float v0 = acc[0][j] + bc0;
        float v1 = (c1 < 31) ? (acc[1][j] + bc1) : -1e30f;
        float mx = fmaxf(v0, v1);
        for (int m = 1; m < 16; m <<= 1) mx = fmaxf(mx, __shfl_xor(mx, m, 16));
        float e0 = __expf(v0 - mx);
        float e1 = (c1 < 31) ? __expf(v1 - mx) : 0.f;
        float ssum = e0 + e1;
        for (int m = 1; m < 16; m <<= 1) ssum += __shfl_xor(ssum, m, 16);
        float inv = 1.f / ssum;
        float conf0 = e0 * inv, conf1 = e1 * inv;
        int lab;
        if (is_src) {
            lab = labels[row];
        } else {
            float bv; int bi;
            if (v0 >= v1) { bv = v0; bi = c0; } else { bv = v1; bi = c1; }
            for (int m = 1; m < 16; m <<= 1) {
                float ov = __shfl_xor(bv, m, 16);
                int oi = __shfl_xor(bi, m, 16);
                if (ov > bv || (ov == bv && oi < bi)) { bv = ov; bi = oi; }
            }
            lab = bi;
        }
        float tc = (c0 == lab ? conf0 : 0.f) + (c1 == lab ? conf1 : 0.f);
        for (int m = 1; m < 16; m <<= 1) tc += __shfl_xor(tc, m, 16);
        float ex = fmaxf(c0 == lab ? -1.f : conf0,
                         (c1 == lab || c1 >= 31) ? -1.f : conf1);
        for (int m = 1; m < 16; m <<= 1) ex = fmaxf(ex, __shfl_xor(ex, m, 16));
        if (c0 == 0) out_margin[row] = tc - ex;
        if (is_src) {
            float vl = (c0 == lab) ? v0 : ((c1 == lab) ? v1 : -1e30f);
            for (int m = 1; m < 16; m <<= 1) vl = fmaxf(vl, __shfl_xor(vl, m, 16));
            if (c0 == 0) ce_local += -(vl - mx - __logf(ssum));
        }
    }
    if (is_src) {
        ce_local += __shfl_xor(ce_local, 16);
        ce_local += __shfl_xor(ce_local, 32);
        if (lane == 0) atomicAdd(ce_acc, ce_local);   // 64 atomics total: fine
    }
}

// ---------------- kernel 6: pairwise d2 -> exp partial sums (no atomics) -
// 128x128 tile, K=256 staged in 2 halves of 64KB LDS
__launch_bounds__(256)
__global__ void k_pairwise(const uint16_t* __restrict__ Y, const float* __restrict__ s2t2,
                           float* __restrict__ gk_part) {
    __shared__ __align__(16) uint8_t lds[65536];  // A 32KB @0, B 32KB @32768
    int tid = threadIdx.x, lane = tid & 63, w = tid >> 6;
    int m0 = blockIdx.x * 128, n0 = blockIdx.y * 128;
    int cc = (lane >> 4) ^ (lane & 3) ^ ((lane >> 2) & 3);
    int wm = (w & 1) * 64, wn = (w >> 1) * 64;
    f32x4 acc[4][4] = {};
    for (int h = 0; h < 2; ++h) {
        if (h) __syncthreads();
        int k0 = h * 128;
        for (int i = 0; i < 8; ++i) {
            int s = w * 8 + i;
            int kb = s >> 3, r0 = (s & 7) * 16;
            int r = r0 + (lane >> 2), p = lane & 3;
            int c = p ^ (r & 3) ^ ((r >> 2) & 3);
            gl_lds16(Y + (size_t)(m0 + r) * 256 + k0 + kb * 32 + c * 8, lds + s * 1024);
            gl_lds16(Y + (size_t)(4096 + n0 + r) * 256 + k0 + kb * 32 + c * 8,
                     lds + 32768 + s * 1024);
        }
        __syncthreads();
        for (int kb = 0; kb < 4; ++kb) {
            bf16x8 a[4], b[4];
            for (int mi = 0; mi < 4; ++mi) {
                int r = wm + mi * 16 + (lane & 15);
                a[mi] = *(const bf16x8*)(lds + kb * 8192 + r * 64 + cc * 16);
            }
            for (int nf = 0; nf < 4; ++nf) {
                int rn = wn + nf * 16 + (lane & 15);
                b[nf] = *(const bf16x8*)(lds + 32768 + kb * 8192 + rn * 64 + cc * 16);
            }
            for (int mi = 0; mi < 4; ++mi)
                for (int nf = 0; nf < 4; ++nf)
                    acc[mi][nf] = __builtin_amdgcn_mfma_f32_16x16x32_bf16(
                        a[mi], b[nf], acc[mi][nf], 0, 0, 0);
        }
    }
    float t2v[4];
    for (int nf = 0; nf < 4; ++nf)
        t2v[nf] = s2t2[4096 + n0 + wn + nf * 16 + (lane & 15)];
    float g1 = 0.f, g5 = 0.f;
    for (int mi = 0; mi < 4; ++mi) {
        int rbase = m0 + wm + mi * 16 + (lane >> 4) * 4;
        float s2v[4];
        for (int j = 0; j < 4; ++j) s2v[j] = s2t2[rbase + j];
        for (int nf = 0; nf < 4; ++nf)
            for (int j = 0; j < 4; ++j) {
                float d2 = s2v[j] + t2v[nf] - 2.f * acc[mi][nf][j];
                d2 = fmaxf(d2, 0.f);
                g1 += __expf(-0.5f * d2);
                g5 += __expf(-0.02f * d2);
            }
    }
    for (int m = 1; m < 64; m <<= 1) { g1 += __shfl_xor(g1, m); g5 += __shfl_xor(g5, m); }
    // block-level reduce (reuse LDS), one plain store per block
    __syncthreads();
    float* red = (float*)lds;
    if (lane == 0) { red[w * 2] = g1; red[w * 2 + 1] = g5; }
    __syncthreads();
    if (tid == 0) {
        int bid = blockIdx.y * 32 + blockIdx.x;
        gk_part[bid * 2]     = red[0] + red[2] + red[4] + red[6];
        gk_part[bid * 2 + 1] = red[1] + red[3] + red[5] + red[7];
    }
}

// ---------------- kernel 7: finalize scalars ----------------------------
__global__ void k_finalize(const float* __restrict__ colsum_part,
                           const float* __restrict__ gk_part,
                           const float* __restrict__ accs, float* __restrict__ d_out) {
    __shared__ float red[12];
    int tid = threadIdx.x, lane = tid & 63, w = tid >> 6;
    float cs = 0.f, ct = 0.f;
    for (int b = 0; b < 64; ++b)  cs += colsum_part[b * 256 + tid];
    for (int b = 64; b < 128; ++b) ct += colsum_part[b * 256 + tid];
    float delta = (cs - ct) * (1.f / 4096.f);
    float sq = delta * delta;
    float g1 = 0.f, g5 = 0.f;
    for (int i = 0; i < 4; ++i) {
        int p = tid * 4 + i;
        g1 += gk_part[p * 2];
        g5 += gk_part[p * 2 + 1];
    }
    for (int m = 1; m < 64; m <<= 1) {
        sq += __shfl_xor(sq, m);
        g1 += __shfl_xor(g1, m);
        g5 += __shfl_xor(g5, m);
    }
    if (lane == 0) { red[w * 3] = sq; red[w * 3 + 1] = g1; red[w * 3 + 2] = g5; }
    __syncthreads();
    if (tid == 0) {
        d_out[0] = accs[0] * (1.f / 4096.f);
        d_out[1] = red[0] + red[3] + red[6] + red[9];
        d_out[2] = (red[1] + red[4] + red[7] + red[10]) * 5.9604644775390625e-08f;
        d_out[3] = (red[2] + red[5] + red[8] + red[11]) * 5.9604644775390625e-08f;
    }
}

extern "C" void kernel_launch(void* const* d_in, const int* in_sizes, int n_in,
                              void* d_out, int out_size, void* d_ws, size_t ws_size,
                              hipStream_t stream) {
    const float* source = (const float*)d_in[0];
    const float* target = (const float*)d_in[1];
    const float* Wb     = (const float*)d_in[2];
    const float* bb     = (const float*)d_in[3];
    const float* Wc     = (const float*)d_in[4];
    const float* bc     = (const float*)d_in[5];
    const int*   labels = (const int*)d_in[6];
    float* out = (float*)d_out;
    uint8_t* ws = (uint8_t*)d_ws;

    uint16_t* Y    = (uint16_t*)(ws);                 // 8192*256*2 = 4 MB
    uint16_t* WbT  = (uint16_t*)(ws + 4194304);       // 1 MB (dead after k_bottleneck)
    uint16_t* WcT  = (uint16_t*)(ws + 5242880);       // 16 KB
    float*    s2t2 = (float*)(ws + 5259264);          // 32 KB
    float*    accs = (float*)(ws + 5292032);          // [ce, pad...]
    // alias the dead WbT region (only read by k_bottleneck, which runs first):
    float*    colsum_part = (float*)(ws + 4194304);             // 128*256 fl = 128 KB
    float*    gk_part     = (float*)(ws + 4194304 + 131072);    // 1024*2 fl = 8 KB

    k_init<<<1, 256, 0, stream>>>(Wc, WcT, accs);
    k_transpose_wb<<<dim3(64, 8), 256, 0, stream>>>(Wb, WbT);
    k_bottleneck<<<512, 256, 0, stream>>>(source, target, WbT, bb, Y);
    k_rowstats<<<2048, 256, 0, stream>>>(Y, s2t2);
    k_colsum<<<128, 256, 0, stream>>>(Y, colsum_part);
    k_classifier<<<128, 256, 0, stream>>>(Y, WcT, bc, labels, out + 4, accs);
    k_pairwise<<<dim3(32, 32), 256, 0, stream>>>(Y, s2t2, gk_part);
    k_finalize<<<1, 256, 0, stream>>>(colsum_part, gk_part, accs, out);
}